// Round 1
// baseline (140.463 us; speedup 1.0000x reference)
//
#include <hip/hip_runtime.h>
#include <hip/hip_bf16.h>

#define NN 1024
#define LOG2E 1.44269504088896f

typedef __attribute__((ext_vector_type(8))) short short8;
typedef __attribute__((ext_vector_type(4))) float floatx4;
typedef __attribute__((ext_vector_type(4))) int intx4;
typedef __attribute__((ext_vector_type(2))) int intx2;

// fast f32->bf16 (round-half-up) pack of two floats into one dword
static __device__ __forceinline__ unsigned pk2(float f0, float f1) {
    unsigned u0 = __float_as_uint(f0) + 0x8000u;
    unsigned u1 = __float_as_uint(f1) + 0x8000u;
    return __builtin_amdgcn_perm(u1, u0, 0x07060302u);   // [u1.hi16 : u0.hi16]
}
static __device__ __forceinline__ short8 pk8(floatx4 v0, floatx4 v1) {
    union { intx4 i; short8 s; } u;
    u.i[0] = (int)pk2(v0[0], v0[1]); u.i[1] = (int)pk2(v0[2], v0[3]);
    u.i[2] = (int)pk2(v1[0], v1[1]); u.i[3] = (int)pk2(v1[2], v1[3]);
    return u.s;
}

// ================= K0: prep — WTb transpose, pwb cast, adj bitmask =================
__global__ __launch_bounds__(256) void prep_kernel(
    const float* __restrict__ W, const float* __restrict__ proj_w,
    const int* __restrict__ adj,
    __hip_bfloat16* __restrict__ WTb,    // [256 o][256 k], o = hh*64+d
    __hip_bfloat16* __restrict__ pwb,    // [256 o][256 k]
    unsigned* __restrict__ adjm)         // [1024][32]
{
    int blk = blockIdx.x, t = threadIdx.x;
    if (blk < 16) {
        int o = blk * 16 + (t >> 4);
        int hh = o >> 6, d = o & 63;
        #pragma unroll
        for (int kk = 0; kk < 16; ++kk) {
            int k = (t & 15) + 16 * kk;
            WTb[(size_t)o * 256 + k] = __float2bfloat16(W[((size_t)hh * 256 + k) * 64 + d]);
        }
    } else if (blk < 32) {
        size_t base = (size_t)(blk - 16) * 4096 + (size_t)t * 16;
        #pragma unroll
        for (int k = 0; k < 16; k += 8) {
            floatx4 v0 = *(const floatx4*)(proj_w + base + k);
            floatx4 v1 = *(const floatx4*)(proj_w + base + k + 4);
            *(short8*)(pwb + base + k) = pk8(v0, v1);
        }
    } else {
        int n = (blk - 32) * 8 + (t >> 5);
        int wd = t & 31;
        const int* arow = adj + (size_t)n * NN + wd * 32;
        unsigned bits = 0;
        #pragma unroll
        for (int j4 = 0; j4 < 8; ++j4) {
            intx4 v = *(const intx4*)(arow + j4 * 4);
            #pragma unroll
            for (int j = 0; j < 4; ++j) if (v[j] != 0) bits |= (1u << (j4 * 4 + j));
        }
        adjm[(size_t)n * 32 + wd] = bits;
    }
}

// ================= K1: Wh GEMM — direct global->VGPR B-fragments (zero-reuse LDS staging removed) =================
// grid = 512 x 256t (4 waves). Wave w = d-slice w; tile j = head j (ct = w + 4j).
// B-frag for lane (rl,q), step k0 is the contiguous 16B WTb[(ct*16+rl)*256 + k0*32 + q*8]
// (the old XOR-swizzled store/read pair cancels to exactly this address).
__global__ __launch_bounds__(256) void wh_kernel(
    const float* __restrict__ h,
    const __hip_bfloat16* __restrict__ WTb,
    const float* __restrict__ a1, const float* __restrict__ a2,
    __hip_bfloat16* __restrict__ WhT,   // [B*H][64][NN]
    float* __restrict__ si, float* __restrict__ sj)   // PRESCALED by log2e
{
    int t = threadIdx.x;
    int w = t >> 6, l = t & 63;
    int rl = l & 15, q = l >> 4;
    int r0 = blockIdx.x * 16;
    int bb = r0 >> 10, n0 = r0 & 1023;

    __shared__ float redsi[4][4][16];
    __shared__ float redsj[4][4][16];

    // A-frags from h (f32 -> bf16 pack)
    short8 af[8];
    const float* Arow = h + (size_t)(r0 + rl) * 256 + q * 8;
    #pragma unroll
    for (int k0 = 0; k0 < 8; ++k0) {
        floatx4 v0 = *(const floatx4*)(Arow + k0 * 32);
        floatx4 v1 = *(const floatx4*)(Arow + k0 * 32 + 4);
        af[k0] = pk8(v0, v1);
    }

    #pragma unroll
    for (int j = 0; j < 4; ++j) {       // ct = w + 4j -> head j, d-slice w
        int ct = w + 4 * j;
        const __hip_bfloat16* Bp = WTb + (size_t)(ct * 16 + rl) * 256 + q * 8;
        floatx4 acc = {0.f, 0.f, 0.f, 0.f};
        #pragma unroll
        for (int k0 = 0; k0 < 8; ++k0) {
            short8 bf = *(const short8*)(Bp + k0 * 32);
            acc = __builtin_amdgcn_mfma_f32_16x16x32_bf16(af[k0], bf, acc, 0, 0, 0);
        }

        // WhT[bh = bb*4+j][d = w*16+rl][n = n0+q*4 ..]
        intx2 pr;
        pr[0] = (int)pk2(acc[0], acc[1]);
        pr[1] = (int)pk2(acc[2], acc[3]);
        *(intx2*)(WhT + ((size_t)(bb * 4 + j) * 64 + w * 16 + rl) * NN + n0 + q * 4) = pr;

        // si/sj partials (prescaled by log2e), reduce over this wave's 16 d's
        float av1 = a1[j * 64 + w * 16 + rl] * LOG2E;
        float av2 = a2[j * 64 + w * 16 + rl] * LOG2E;
        #pragma unroll
        for (int i = 0; i < 4; ++i) {
            float p1 = acc[i] * av1, p2 = acc[i] * av2;
            #pragma unroll
            for (int off = 1; off < 16; off <<= 1) {
                p1 += __shfl_xor(p1, off, 64);
                p2 += __shfl_xor(p2, off, 64);
            }
            if (rl == 0) { redsi[w][j][q * 4 + i] = p1; redsj[w][j][q * 4 + i] = p2; }
        }
    }
    __syncthreads();

    if (t < 64) {
        int head = t >> 4, row = t & 15;
        si[(size_t)(bb * 4 + head) * NN + n0 + row] =
            redsi[0][head][row] + redsi[1][head][row] + redsi[2][head][row] + redsi[3][head][row];
    } else if (t < 128) {
        int u = t - 64;
        int head = u >> 4, row = u & 15;
        sj[(size_t)(bb * 4 + head) * NN + n0 + row] =
            redsj[0][head][row] + redsj[1][head][row] + redsj[2][head][row] + redsj[3][head][row];
    }
}

// ================= K2: attn (direct-register B-frags, prefetch rotate) + proj + LN fused =================
// grid = 512 x 256t. Block = (b, 16-token tile); wave w = head w in attn phase.
// No LDS staging of WhT/pwb (zero reuse): per-fragment 16B global loads, L2-resident.
// LDS only for the genuine transposes: pl (P rows -> MFMA A-frags, same-wave) and hm (head concat, barrier).
__global__ __launch_bounds__(256) void attn_proj_kernel(
    const unsigned* __restrict__ adjm,
    const __hip_bfloat16* __restrict__ WhT,
    const float* __restrict__ si, const float* __restrict__ sj,
    const __hip_bfloat16* __restrict__ pwb,
    const float* __restrict__ h,
    const float* __restrict__ proj_b, const float* __restrict__ gamma,
    const float* __restrict__ beta,
    float* __restrict__ out)
{
    __shared__ __align__(16) __hip_bfloat16 pl[4][16][72];
    __shared__ float rinvs[4][16];
    __shared__ __align__(16) __hip_bfloat16 hm[16][264];
    __shared__ float red[2][4][16];

    int bx = blockIdx.x, t = threadIdx.x;
    int w = t >> 6, l = t & 63;
    int rl = l & 15, q = l >> 4;
    int b = bx >> 6, n0 = (bx & 63) * 16;
    int bh = b * 4 + w;
    int r0 = bx * 16;

    int r = l >> 2, cg = l & 3;          // score roles: row r, 16-entry chunk cg
    float sii = si[(size_t)bh * NN + n0 + r];
    const float* sjr = sj + (size_t)bh * NN;
    const unsigned* amrow = adjm + (size_t)(n0 + r) * 32;

    float lsum = 0.f;
    floatx4 acc[4] = { {0,0,0,0}, {0,0,0,0}, {0,0,0,0}, {0,0,0,0} };

    const __hip_bfloat16* Bhead = WhT + (size_t)bh * 64 * NN;

    // prefetch B-frags for it=0: frag u = (ks=u>>2, dt=u&3) -> 16B at [d=dt*16+rl][m = ks*32 + q*8]
    short8 bf[8];
    #pragma unroll
    for (int u = 0; u < 8; ++u) {
        int ks = u >> 2, dt = u & 3;
        bf[u] = *(const short8*)(Bhead + (size_t)(dt * 16 + rl) * NN + ks * 32 + q * 8);
    }

    #pragma unroll 2
    for (int it = 0; it < 16; ++it) {
        int m0 = it * 64;
        // issue next-tile frag loads first: register dests, compiler pipelines them under scores
        short8 bn[8];
        if (it < 15) {
            #pragma unroll
            for (int u = 0; u < 8; ++u) {
                int ks = u >> 2, dt = u & 3;
                bn[u] = *(const short8*)(Bhead + (size_t)(dt * 16 + rl) * NN + m0 + 64 + ks * 32 + q * 8);
            }
        }
        // ---- scores(it) ----
        {
            int mb = m0 + cg * 16;
            unsigned bits = amrow[(m0 >> 5) + (cg >> 1)] >> ((cg & 1) * 16);
            #pragma unroll
            for (int c4 = 0; c4 < 4; ++c4) {
                floatx4 s4 = *(const floatx4*)(sjr + mb + c4 * 4);
                float pv[4];
                #pragma unroll
                for (int k = 0; k < 4; ++k) {
                    float x = sii + s4[k];
                    x = fmaxf(x, 0.2f * x);                               // leaky (prescaled)
                    x = ((bits >> (c4 * 4 + k)) & 1u) ? x : -1e9f;        // mask -> exp2 = 0
                    pv[k] = exp2f(x);
                    lsum += pv[k];
                }
                intx2 two;
                two[0] = (int)pk2(pv[0], pv[1]);
                two[1] = (int)pk2(pv[2], pv[3]);
                *(intx2*)(&pl[w][r][cg * 16 + c4 * 4]) = two;
            }
        }
        // ---- MFMA(it): A = pl rows (same-wave DS in-order), B = register frags ----
        #pragma unroll
        for (int ks = 0; ks < 2; ++ks) {
            short8 afr = *(const short8*)(&pl[w][rl][ks * 32 + q * 8]);
            #pragma unroll
            for (int dt = 0; dt < 4; ++dt)
                acc[dt] = __builtin_amdgcn_mfma_f32_16x16x32_bf16(afr, bf[ks * 4 + dt], acc[dt], 0, 0, 0);
        }
        if (it < 15) {
            #pragma unroll
            for (int u = 0; u < 8; ++u) bf[u] = bn[u];
        }
    }

    // softmax denominators: reduce over 4 lanes sharing row r (same-wave)
    lsum += __shfl_xor(lsum, 1, 64);
    lsum += __shfl_xor(lsum, 2, 64);
    if (cg == 0) rinvs[w][r] = 1.f / lsum;
    float riv[4];
    #pragma unroll
    for (int i = 0; i < 4; ++i) riv[i] = rinvs[w][q * 4 + i];

    // head concat into hm (cross-wave -> barrier before reads)
    #pragma unroll
    for (int dt = 0; dt < 4; ++dt) {
        #pragma unroll
        for (int i = 0; i < 4; ++i) {
            unsigned uv = (__float_as_uint(acc[dt][i] * riv[i]) + 0x8000u) >> 16;
            hm[q * 4 + i][w * 64 + dt * 16 + rl] = __ushort_as_bfloat16((unsigned short)uv);
        }
    }
    __syncthreads();    // hm complete (all heads)

    // ---- proj: A from hm, B direct from pwb; wave w tiles ct = w + 4j ----
    short8 paf[8];
    #pragma unroll
    for (int k0 = 0; k0 < 8; ++k0) paf[k0] = *(const short8*)(&hm[rl][q * 8 + k0 * 32]);

    floatx4 pacc[4];
    #pragma unroll
    for (int j = 0; j < 4; ++j) {
        int ct = w + 4 * j;
        const __hip_bfloat16* Bp = pwb + (size_t)(ct * 16 + rl) * 256 + q * 8;
        floatx4 a = {0.f, 0.f, 0.f, 0.f};
        #pragma unroll
        for (int k0 = 0; k0 < 8; ++k0) {
            short8 bfp = *(const short8*)(Bp + k0 * 32);
            a = __builtin_amdgcn_mfma_f32_16x16x32_bf16(paf[k0], bfp, a, 0, 0, 0);
        }
        pacc[j] = a;
    }

    // bias + residual + LayerNorm
    float ps[4] = {0.f, 0.f, 0.f, 0.f};
    #pragma unroll
    for (int j = 0; j < 4; ++j) {
        int col = (w + j * 4) * 16 + rl;
        float pb = proj_b[col];
        #pragma unroll
        for (int i = 0; i < 4; ++i) {
            float v = pacc[j][i] + pb + h[(size_t)(r0 + q * 4 + i) * 256 + col];
            pacc[j][i] = v;
            ps[i] += v;
        }
    }
    #pragma unroll
    for (int i = 0; i < 4; ++i) {
        float s = ps[i];
        #pragma unroll
        for (int off = 1; off < 16; off <<= 1) s += __shfl_xor(s, off, 64);
        ps[i] = s;
    }
    if (rl == 0) {
        for (int i = 0; i < 4; ++i) red[0][w][q * 4 + i] = ps[i];
    }
    __syncthreads();
    float mu[4];
    #pragma unroll
    for (int i = 0; i < 4; ++i) {
        int row = q * 4 + i;
        mu[i] = (red[0][0][row] + red[0][1][row] + red[0][2][row] + red[0][3][row]) * (1.f / 256.f);
    }
    float vs[4] = {0.f, 0.f, 0.f, 0.f};
    #pragma unroll
    for (int j = 0; j < 4; ++j) {
        #pragma unroll
        for (int i = 0; i < 4; ++i) { float cv = pacc[j][i] - mu[i]; vs[i] += cv * cv; }
    }
    #pragma unroll
    for (int i = 0; i < 4; ++i) {
        float s = vs[i];
        #pragma unroll
        for (int off = 1; off < 16; off <<= 1) s += __shfl_xor(s, off, 64);
        vs[i] = s;
    }
    if (rl == 0) {
        for (int i = 0; i < 4; ++i) red[1][w][q * 4 + i] = vs[i];
    }
    __syncthreads();
    float rs[4];
    #pragma unroll
    for (int i = 0; i < 4; ++i) {
        int row = q * 4 + i;
        float var = (red[1][0][row] + red[1][1][row] + red[1][2][row] + red[1][3][row]) * (1.f / 256.f);
        rs[i] = rsqrtf(var + 1e-5f);
    }
    #pragma unroll
    for (int j = 0; j < 4; ++j) {
        int col = (w + j * 4) * 16 + rl;
        float g = gamma[col], be = beta[col];
        #pragma unroll
        for (int i = 0; i < 4; ++i)
            out[(size_t)(r0 + q * 4 + i) * 256 + col] = (pacc[j][i] - mu[i]) * rs[i] * g + be;
    }
}

extern "C" void kernel_launch(void* const* d_in, const int* in_sizes, int n_in,
                              void* d_out, int out_size, void* d_ws, size_t ws_size,
                              hipStream_t stream) {
    const float* h      = (const float*)d_in[0];
    const int*   adj    = (const int*)d_in[1];
    const float* W      = (const float*)d_in[2];
    const float* a1     = (const float*)d_in[3];
    const float* a2     = (const float*)d_in[4];
    const float* proj_w = (const float*)d_in[5];
    const float* proj_b = (const float*)d_in[6];
    const float* gamma  = (const float*)d_in[7];
    const float* beta   = (const float*)d_in[8];
    float* out = (float*)d_out;

    char* ws = (char*)d_ws;
    __hip_bfloat16* WhT = (__hip_bfloat16*)ws;   ws += (size_t)32 * 64 * NN * 2;   // 4 MB
    __hip_bfloat16* WTb = (__hip_bfloat16*)ws;   ws += 256 * 256 * 2;              // 128 KB
    __hip_bfloat16* pwb = (__hip_bfloat16*)ws;   ws += 256 * 256 * 2;              // 128 KB
    float* si = (float*)ws;                      ws += (size_t)32 * NN * 4;        // 128 KB
    float* sj = (float*)ws;                      ws += (size_t)32 * NN * 4;        // 128 KB
    unsigned* adjm = (unsigned*)ws;              ws += (size_t)NN * 32 * 4;        // 128 KB

    prep_kernel<<<160, 256, 0, stream>>>(W, proj_w, adj, WTb, pwb, adjm);
    wh_kernel<<<512, 256, 0, stream>>>(h, WTb, a1, a2, WhT, si, sj);
    attn_proj_kernel<<<512, 256, 0, stream>>>(adjm, WhT, si, sj, pwb, h, proj_b, gamma, beta, out);
}

// Round 2
// 122.656 us; speedup vs baseline: 1.1452x; 1.1452x over previous
//
#include <hip/hip_runtime.h>
#include <hip/hip_bf16.h>

#define NN 1024
#define LOG2E 1.44269504088896f

typedef __attribute__((ext_vector_type(8))) short short8;
typedef __attribute__((ext_vector_type(4))) float floatx4;
typedef __attribute__((ext_vector_type(4))) int intx4;
typedef __attribute__((ext_vector_type(2))) int intx2;

#define WAIT_VM0()   asm volatile("s_waitcnt vmcnt(0)" ::: "memory")
#define WAIT_LGKM0() asm volatile("s_waitcnt lgkmcnt(0)" ::: "memory")

// fast f32->bf16 (round-half-up) pack of two floats into one dword
static __device__ __forceinline__ unsigned pk2(float f0, float f1) {
    unsigned u0 = __float_as_uint(f0) + 0x8000u;
    unsigned u1 = __float_as_uint(f1) + 0x8000u;
    return __builtin_amdgcn_perm(u1, u0, 0x07060302u);   // [u1.hi16 : u0.hi16]
}
static __device__ __forceinline__ short8 pk8(floatx4 v0, floatx4 v1) {
    union { intx4 i; short8 s; } u;
    u.i[0] = (int)pk2(v0[0], v0[1]); u.i[1] = (int)pk2(v0[2], v0[3]);
    u.i[2] = (int)pk2(v1[0], v1[1]); u.i[3] = (int)pk2(v1[2], v1[3]);
    return u.s;
}
// async global->LDS, 16B/lane, dest = ldsbase + lane*16
static __device__ __forceinline__ void load_lds16(const void* gsrc, void* lds) {
    __builtin_amdgcn_global_load_lds(
        (const __attribute__((address_space(1))) void*)gsrc,
        (__attribute__((address_space(3))) void*)lds, 16, 0, 0);
}

// ================= K0: prep — WTb transpose, pwb cast, adj bitmask =================
__global__ __launch_bounds__(256) void prep_kernel(
    const float* __restrict__ W, const float* __restrict__ proj_w,
    const int* __restrict__ adj,
    __hip_bfloat16* __restrict__ WTb,    // [256 o][256 k], o = hh*64+d
    __hip_bfloat16* __restrict__ pwb,    // [256 o][256 k]
    unsigned* __restrict__ adjm)         // [1024][32]
{
    int blk = blockIdx.x, t = threadIdx.x;
    if (blk < 16) {
        int o = blk * 16 + (t >> 4);
        int hh = o >> 6, d = o & 63;
        #pragma unroll
        for (int kk = 0; kk < 16; ++kk) {
            int k = (t & 15) + 16 * kk;
            WTb[(size_t)o * 256 + k] = __float2bfloat16(W[((size_t)hh * 256 + k) * 64 + d]);
        }
    } else if (blk < 32) {
        size_t base = (size_t)(blk - 16) * 4096 + (size_t)t * 16;
        #pragma unroll
        for (int k = 0; k < 16; k += 8) {
            floatx4 v0 = *(const floatx4*)(proj_w + base + k);
            floatx4 v1 = *(const floatx4*)(proj_w + base + k + 4);
            *(short8*)(pwb + base + k) = pk8(v0, v1);
        }
    } else {
        int n = (blk - 32) * 8 + (t >> 5);
        int wd = t & 31;
        const int* arow = adj + (size_t)n * NN + wd * 32;
        unsigned bits = 0;
        #pragma unroll
        for (int j4 = 0; j4 < 8; ++j4) {
            intx4 v = *(const intx4*)(arow + j4 * 4);
            #pragma unroll
            for (int j = 0; j < 4; ++j) if (v[j] != 0) bits |= (1u << (j4 * 4 + j));
        }
        adjm[(size_t)n * 32 + wd] = bits;
    }
}

// ================= K1: Wh GEMM — async single-buffer staging + explicit fences (round-0 proven) =================
// grid = 512 x 256t (4 waves). Wave w = d-slice w; tile j = head j (ct = w + 4j).
__global__ __launch_bounds__(256) void wh_kernel(
    const float* __restrict__ h,
    const __hip_bfloat16* __restrict__ WTb,
    const float* __restrict__ a1, const float* __restrict__ a2,
    __hip_bfloat16* __restrict__ WhT,   // [B*H][64][NN]
    float* __restrict__ si, float* __restrict__ sj)   // PRESCALED by log2e
{
    int t = threadIdx.x;
    int w = t >> 6, l = t & 63;
    int rl = l & 15, q = l >> 4;
    int r0 = blockIdx.x * 16;
    int bb = r0 >> 10, n0 = r0 & 1023;

    // wave-private single-buffer B tile: 16 rows x 256 k, UNPADDED, XOR-swizzled
    __shared__ __align__(16) __hip_bfloat16 bst[4][4096];
    __shared__ float redsi[4][4][16];
    __shared__ float redsj[4][4][16];

    // A-frags from h (f32 -> bf16 pack)
    short8 af[8];
    const float* Arow = h + (size_t)(r0 + rl) * 256 + q * 8;
    #pragma unroll
    for (int k0 = 0; k0 < 8; ++k0) {
        floatx4 v0 = *(const floatx4*)(Arow + k0 * 32);
        floatx4 v1 = *(const floatx4*)(Arow + k0 * 32 + 4);
        af[k0] = pk8(v0, v1);
    }

    // stage tile j=0 (ct = w): inst k covers rows k*2+(l>>5); swizzle g = (l&31) ^ (row&7)
    #pragma unroll
    for (int k = 0; k < 8; ++k) {
        int row = k * 2 + (l >> 5);
        int g = (l & 31) ^ (row & 7);
        load_lds16(WTb + (size_t)w * 4096 + row * 256 + g * 8, &bst[w][k * 512]);
    }

    #pragma unroll
    for (int j = 0; j < 4; ++j) {       // ct = w + 4j -> head j, d-slice w
        WAIT_VM0();                      // tile-j DMAs landed in LDS
        floatx4 acc = {0.f, 0.f, 0.f, 0.f};
        #pragma unroll
        for (int k0 = 0; k0 < 8; ++k0) {
            int p = ((k0 << 2) + q) ^ (rl & 7);
            short8 bf = *(const short8*)(&bst[w][rl * 256 + p * 8]);
            acc = __builtin_amdgcn_mfma_f32_16x16x32_bf16(af[k0], bf, acc, 0, 0, 0);
        }
        WAIT_LGKM0();                    // ds_reads retired to VGPRs; LDS may be overwritten
        if (j < 3) {                     // issue loads(j+1); epilogue below is the blanket
            int ctn = w + 4 * (j + 1);
            #pragma unroll
            for (int k = 0; k < 8; ++k) {
                int row = k * 2 + (l >> 5);
                int g = (l & 31) ^ (row & 7);
                load_lds16(WTb + (size_t)ctn * 4096 + row * 256 + g * 8, &bst[w][k * 512]);
            }
        }

        // WhT[bh = bb*4+j][d = w*16+rl][n = n0+q*4 ..]
        intx2 pr;
        pr[0] = (int)pk2(acc[0], acc[1]);
        pr[1] = (int)pk2(acc[2], acc[3]);
        *(intx2*)(WhT + ((size_t)(bb * 4 + j) * 64 + w * 16 + rl) * NN + n0 + q * 4) = pr;

        // si/sj partials (prescaled by log2e), reduce over this wave's 16 d's
        float av1 = a1[j * 64 + w * 16 + rl] * LOG2E;
        float av2 = a2[j * 64 + w * 16 + rl] * LOG2E;
        #pragma unroll
        for (int i = 0; i < 4; ++i) {
            float p1 = acc[i] * av1, p2 = acc[i] * av2;
            #pragma unroll
            for (int off = 1; off < 16; off <<= 1) {
                p1 += __shfl_xor(p1, off, 64);
                p2 += __shfl_xor(p2, off, 64);
            }
            if (rl == 0) { redsi[w][j][q * 4 + i] = p1; redsj[w][j][q * 4 + i] = p2; }
        }
    }
    __syncthreads();

    if (t < 64) {
        int head = t >> 4, row = t & 15;
        si[(size_t)(bb * 4 + head) * NN + n0 + row] =
            redsi[0][head][row] + redsi[1][head][row] + redsi[2][head][row] + redsi[3][head][row];
    } else if (t < 128) {
        int u = t - 64;
        int head = u >> 4, row = u & 15;
        sj[(size_t)(bb * 4 + head) * NN + n0 + row] =
            redsj[0][head][row] + redsj[1][head][row] + redsj[2][head][row] + redsj[3][head][row];
    }
}

// ================= K2: attn (8-wave m-split, wave-private DMA tiles) + proj + LN fused =================
// grid = 512 x 512t (8 waves). Wave w: head hh = w&3, m-half e = w>>2.
// Each wave: own 64d x 32m staged tile (4 DMA/iter), half the scores (8 exp2/lane/iter),
// 4 MFMA K=32 per iter. Partial acc/lsum combined once at the end via LDS.
__global__ __launch_bounds__(512, 4) void attn_proj_kernel(
    const unsigned* __restrict__ adjm,
    const __hip_bfloat16* __restrict__ WhT,
    const float* __restrict__ si, const float* __restrict__ sj,
    const __hip_bfloat16* __restrict__ pwb,
    const float* __restrict__ h,
    const float* __restrict__ proj_b, const float* __restrict__ gamma,
    const float* __restrict__ beta,
    float* __restrict__ out)
{
    __shared__ __align__(16) __hip_bfloat16 bst[8][2048];   // per-wave 64d x 32m tiles (XOR-swizzled)
    __shared__ __align__(16) __hip_bfloat16 pl[8][16][40];  // per-wave P half-tiles (16 x 32, pad 40)
    __shared__ float lsums[2][4][16];                       // [e][head][row] partial denoms
    __shared__ __align__(16) __hip_bfloat16 hm[16][264];
    __shared__ float red[2][8][16];
    // acc-combine buffer overlays bst (dead after main loop): [head][lane][16 vals, pad 20]
    float (*accx)[64][20] = reinterpret_cast<float (*)[64][20]>(&bst[0][0]);

    int bx = blockIdx.x, t = threadIdx.x;
    int w = t >> 6, l = t & 63;
    int hh = w & 3, e = w >> 2;
    int rl = l & 15, q = l >> 4;
    int b = bx >> 6, n0 = (bx & 63) * 16;
    int bh = b * 4 + hh;
    int r0 = bx * 16;

    int r = l >> 2, cg = l & 3;          // score roles: row r, 8-entry chunk cg (within 32-m half)
    float sii = si[(size_t)bh * NN + n0 + r];
    const float* sjr = sj + (size_t)bh * NN;
    const unsigned* amrow = adjm + (size_t)(n0 + r) * 32;

    float lsum = 0.f;
    floatx4 acc[4] = { {0,0,0,0}, {0,0,0,0}, {0,0,0,0}, {0,0,0,0} };

    const __hip_bfloat16* Bhead = WhT + (size_t)bh * 64 * NN;

    // DMA lane mapping: load k covers rows k*16+srow (32m = 64B rows, 16 rows / 1KB inst);
    // pre-swizzled source col-group g = c ^ (row&3) so linear LDS dest realizes the XOR layout.
    int srow = l >> 2;                   // 0..15
    int sg = (l & 3) ^ (srow & 3);

    // prologue: issue loads(it=0) for this wave's m-half
    #pragma unroll
    for (int k = 0; k < 4; ++k)
        load_lds16(Bhead + (size_t)(k * 16 + srow) * NN + e * 32 + sg * 8, &bst[w][k * 512]);

    for (int it = 0; it < 16; ++it) {
        int mw = it * 64 + e * 32;       // wave's m-base
        // ---- scores over [mw, mw+32): VALU blanket over the staging latency ----
        {
            unsigned bits = amrow[it * 2 + e] >> (cg * 8);
            int mb = mw + cg * 8;
            #pragma unroll
            for (int c4 = 0; c4 < 2; ++c4) {
                floatx4 s4 = *(const floatx4*)(sjr + mb + c4 * 4);
                float pv[4];
                #pragma unroll
                for (int k = 0; k < 4; ++k) {
                    float x = sii + s4[k];
                    x = fmaxf(x, 0.2f * x);                               // leaky (prescaled)
                    x = ((bits >> (c4 * 4 + k)) & 1u) ? x : -1e9f;        // mask -> exp2 = 0
                    pv[k] = exp2f(x);
                    lsum += pv[k];
                }
                intx2 two;
                two[0] = (int)pk2(pv[0], pv[1]);
                two[1] = (int)pk2(pv[2], pv[3]);
                *(intx2*)(&pl[w][r][cg * 8 + c4 * 4]) = two;
            }
        }
        WAIT_VM0();                      // tile-it DMAs landed in LDS
        // ---- MFMA(it): A = P half-tile (K=32), B = swizzled bst ----
        short8 afr = *(const short8*)(&pl[w][rl][q * 8]);
        #pragma unroll
        for (int dt = 0; dt < 4; ++dt) {
            short8 bfr = *(const short8*)(&bst[w][(dt * 16 + rl) * 32 + (q ^ (rl & 3)) * 8]);
            acc[dt] = __builtin_amdgcn_mfma_f32_16x16x32_bf16(afr, bfr, acc[dt], 0, 0, 0);
        }
        WAIT_LGKM0();                    // ds_reads retired; bst may be overwritten
        if (it < 15) {
            int mwn = mw + 64;
            #pragma unroll
            for (int k = 0; k < 4; ++k)
                load_lds16(Bhead + (size_t)(k * 16 + srow) * NN + mwn + sg * 8, &bst[w][k * 512]);
        }
    }

    // partial softmax denominators: reduce over 4 lanes sharing row r
    lsum += __shfl_xor(lsum, 1, 64);
    lsum += __shfl_xor(lsum, 2, 64);
    if (cg == 0) lsums[e][hh][r] = lsum;

    __syncthreads();    // S1: all waves past last MFMA (bst dead); lsums ready

    if (e == 1) {       // stash partial acc for combine
        #pragma unroll
        for (int dt = 0; dt < 4; ++dt) {
            #pragma unroll
            for (int i = 0; i < 4; ++i)
                accx[hh][l][dt * 4 + i] = acc[dt][i];
        }
    }
    __syncthreads();    // S2: accx ready

    if (e == 0) {       // combine halves, apply 1/denominator, write hm
        float riv[4];
        #pragma unroll
        for (int i = 0; i < 4; ++i)
            riv[i] = 1.f / (lsums[0][hh][q * 4 + i] + lsums[1][hh][q * 4 + i]);
        #pragma unroll
        for (int dt = 0; dt < 4; ++dt) {
            #pragma unroll
            for (int i = 0; i < 4; ++i) {
                float v = acc[dt][i] + accx[hh][l][dt * 4 + i];
                unsigned uv = (__float_as_uint(v * riv[i]) + 0x8000u) >> 16;
                hm[q * 4 + i][hh * 64 + dt * 16 + rl] = __ushort_as_bfloat16((unsigned short)uv);
            }
        }
    }
    __syncthreads();    // S3: hm complete (all heads)

    // ---- proj: A from hm, B direct from L2-hot pwb; wave w tiles ct = w + 8j ----
    short8 paf[8];
    #pragma unroll
    for (int k0 = 0; k0 < 8; ++k0) paf[k0] = *(const short8*)(&hm[rl][q * 8 + k0 * 32]);

    floatx4 pacc[2];
    #pragma unroll
    for (int j = 0; j < 2; ++j) {
        int ct = w + 8 * j;
        const __hip_bfloat16* Bp = pwb + (size_t)(ct * 16 + rl) * 256 + q * 8;
        floatx4 a = {0.f, 0.f, 0.f, 0.f};
        #pragma unroll
        for (int k0 = 0; k0 < 8; ++k0) {
            short8 bfp = *(const short8*)(Bp + k0 * 32);
            a = __builtin_amdgcn_mfma_f32_16x16x32_bf16(paf[k0], bfp, a, 0, 0, 0);
        }
        pacc[j] = a;
    }

    // bias + residual + LayerNorm (8 waves x 2 col-tiles each)
    float ps[4] = {0.f, 0.f, 0.f, 0.f};
    #pragma unroll
    for (int j = 0; j < 2; ++j) {
        int col = (w + 8 * j) * 16 + rl;
        float pb = proj_b[col];
        #pragma unroll
        for (int i = 0; i < 4; ++i) {
            float v = pacc[j][i] + pb + h[(size_t)(r0 + q * 4 + i) * 256 + col];
            pacc[j][i] = v;
            ps[i] += v;
        }
    }
    #pragma unroll
    for (int i = 0; i < 4; ++i) {
        float s = ps[i];
        #pragma unroll
        for (int off = 1; off < 16; off <<= 1) s += __shfl_xor(s, off, 64);
        ps[i] = s;
    }
    if (rl == 0) {
        for (int i = 0; i < 4; ++i) red[0][w][q * 4 + i] = ps[i];
    }
    __syncthreads();
    float mu[4];
    #pragma unroll
    for (int i = 0; i < 4; ++i) {
        int row = q * 4 + i;
        float s = 0.f;
        #pragma unroll
        for (int ww = 0; ww < 8; ++ww) s += red[0][ww][row];
        mu[i] = s * (1.f / 256.f);
    }
    float vs[4] = {0.f, 0.f, 0.f, 0.f};
    #pragma unroll
    for (int j = 0; j < 2; ++j) {
        #pragma unroll
        for (int i = 0; i < 4; ++i) { float cv = pacc[j][i] - mu[i]; vs[i] += cv * cv; }
    }
    #pragma unroll
    for (int i = 0; i < 4; ++i) {
        float s = vs[i];
        #pragma unroll
        for (int off = 1; off < 16; off <<= 1) s += __shfl_xor(s, off, 64);
        vs[i] = s;
    }
    if (rl == 0) {
        for (int i = 0; i < 4; ++i) red[1][w][q * 4 + i] = vs[i];
    }
    __syncthreads();
    float rs[4];
    #pragma unroll
    for (int i = 0; i < 4; ++i) {
        int row = q * 4 + i;
        float s = 0.f;
        #pragma unroll
        for (int ww = 0; ww < 8; ++ww) s += red[1][ww][row];
        rs[i] = rsqrtf(s * (1.f / 256.f) + 1e-5f);
    }
    #pragma unroll
    for (int j = 0; j < 2; ++j) {
        int col = (w + 8 * j) * 16 + rl;
        float g = gamma[col], be = beta[col];
        #pragma unroll
        for (int i = 0; i < 4; ++i)
            out[(size_t)(r0 + q * 4 + i) * 256 + col] = (pacc[j][i] - mu[i]) * rs[i] * g + be;
    }
}

extern "C" void kernel_launch(void* const* d_in, const int* in_sizes, int n_in,
                              void* d_out, int out_size, void* d_ws, size_t ws_size,
                              hipStream_t stream) {
    const float* h      = (const float*)d_in[0];
    const int*   adj    = (const int*)d_in[1];
    const float* W      = (const float*)d_in[2];
    const float* a1     = (const float*)d_in[3];
    const float* a2     = (const float*)d_in[4];
    const float* proj_w = (const float*)d_in[5];
    const float* proj_b = (const float*)d_in[6];
    const float* gamma  = (const float*)d_in[7];
    const float* beta   = (const float*)d_in[8];
    float* out = (float*)d_out;

    char* ws = (char*)d_ws;
    __hip_bfloat16* WhT = (__hip_bfloat16*)ws;   ws += (size_t)32 * 64 * NN * 2;   // 4 MB
    __hip_bfloat16* WTb = (__hip_bfloat16*)ws;   ws += 256 * 256 * 2;              // 128 KB
    __hip_bfloat16* pwb = (__hip_bfloat16*)ws;   ws += 256 * 256 * 2;              // 128 KB
    float* si = (float*)ws;                      ws += (size_t)32 * NN * 4;        // 128 KB
    float* sj = (float*)ws;                      ws += (size_t)32 * NN * 4;        // 128 KB
    unsigned* adjm = (unsigned*)ws;              ws += (size_t)NN * 32 * 4;        // 128 KB

    prep_kernel<<<160, 256, 0, stream>>>(W, proj_w, adj, WTb, pwb, adjm);
    wh_kernel<<<512, 256, 0, stream>>>(h, WTb, a1, a2, WhT, si, sj);
    attn_proj_kernel<<<512, 512, 0, stream>>>(adjm, WhT, si, sj, pwb, h, proj_b, gamma, beta, out);
}

// Round 3
// 122.607 us; speedup vs baseline: 1.1456x; 1.0004x over previous
//
#include <hip/hip_runtime.h>
#include <hip/hip_bf16.h>

#define NN 1024
#define LOG2E 1.44269504088896f

typedef __attribute__((ext_vector_type(8))) short short8;
typedef __attribute__((ext_vector_type(4))) float floatx4;
typedef __attribute__((ext_vector_type(4))) int intx4;
typedef __attribute__((ext_vector_type(2))) int intx2;

#define WAIT_VM0()   asm volatile("s_waitcnt vmcnt(0)" ::: "memory")
#define WAIT_VM4()   asm volatile("s_waitcnt vmcnt(4)" ::: "memory")
#define WAIT_LGKM0() asm volatile("s_waitcnt lgkmcnt(0)" ::: "memory")
#define SCHED_FENCE() asm volatile("" ::: "memory")

// fast f32->bf16 (round-half-up) pack of two floats into one dword
static __device__ __forceinline__ unsigned pk2(float f0, float f1) {
    unsigned u0 = __float_as_uint(f0) + 0x8000u;
    unsigned u1 = __float_as_uint(f1) + 0x8000u;
    return __builtin_amdgcn_perm(u1, u0, 0x07060302u);   // [u1.hi16 : u0.hi16]
}
static __device__ __forceinline__ short8 pk8(floatx4 v0, floatx4 v1) {
    union { intx4 i; short8 s; } u;
    u.i[0] = (int)pk2(v0[0], v0[1]); u.i[1] = (int)pk2(v0[2], v0[3]);
    u.i[2] = (int)pk2(v1[0], v1[1]); u.i[3] = (int)pk2(v1[2], v1[3]);
    return u.s;
}
// async global->LDS, 16B/lane, dest = ldsbase + lane*16
static __device__ __forceinline__ void load_lds16(const void* gsrc, void* lds) {
    __builtin_amdgcn_global_load_lds(
        (const __attribute__((address_space(1))) void*)gsrc,
        (__attribute__((address_space(3))) void*)lds, 16, 0, 0);
}

// ================= K0: prep — WTb transpose, pwb cast, adj bitmask =================
__global__ __launch_bounds__(256) void prep_kernel(
    const float* __restrict__ W, const float* __restrict__ proj_w,
    const int* __restrict__ adj,
    __hip_bfloat16* __restrict__ WTb,    // [256 o][256 k], o = hh*64+d
    __hip_bfloat16* __restrict__ pwb,    // [256 o][256 k]
    unsigned* __restrict__ adjm)         // [1024][32]
{
    int blk = blockIdx.x, t = threadIdx.x;
    if (blk < 16) {
        int o = blk * 16 + (t >> 4);
        int hh = o >> 6, d = o & 63;
        #pragma unroll
        for (int kk = 0; kk < 16; ++kk) {
            int k = (t & 15) + 16 * kk;
            WTb[(size_t)o * 256 + k] = __float2bfloat16(W[((size_t)hh * 256 + k) * 64 + d]);
        }
    } else if (blk < 32) {
        size_t base = (size_t)(blk - 16) * 4096 + (size_t)t * 16;
        #pragma unroll
        for (int k = 0; k < 16; k += 8) {
            floatx4 v0 = *(const floatx4*)(proj_w + base + k);
            floatx4 v1 = *(const floatx4*)(proj_w + base + k + 4);
            *(short8*)(pwb + base + k) = pk8(v0, v1);
        }
    } else {
        int n = (blk - 32) * 8 + (t >> 5);
        int wd = t & 31;
        const int* arow = adj + (size_t)n * NN + wd * 32;
        unsigned bits = 0;
        #pragma unroll
        for (int j4 = 0; j4 < 8; ++j4) {
            intx4 v = *(const intx4*)(arow + j4 * 4);
            #pragma unroll
            for (int j = 0; j < 4; ++j) if (v[j] != 0) bits |= (1u << (j4 * 4 + j));
        }
        adjm[(size_t)n * 32 + wd] = bits;
    }
}

// ================= K1: Wh GEMM — async single-buffer staging + explicit fences (round-0 proven) =================
__global__ __launch_bounds__(256) void wh_kernel(
    const float* __restrict__ h,
    const __hip_bfloat16* __restrict__ WTb,
    const float* __restrict__ a1, const float* __restrict__ a2,
    __hip_bfloat16* __restrict__ WhT,   // [B*H][64][NN]
    float* __restrict__ si, float* __restrict__ sj)   // PRESCALED by log2e
{
    int t = threadIdx.x;
    int w = t >> 6, l = t & 63;
    int rl = l & 15, q = l >> 4;
    int r0 = blockIdx.x * 16;
    int bb = r0 >> 10, n0 = r0 & 1023;

    __shared__ __align__(16) __hip_bfloat16 bst[4][4096];
    __shared__ float redsi[4][4][16];
    __shared__ float redsj[4][4][16];

    short8 af[8];
    const float* Arow = h + (size_t)(r0 + rl) * 256 + q * 8;
    #pragma unroll
    for (int k0 = 0; k0 < 8; ++k0) {
        floatx4 v0 = *(const floatx4*)(Arow + k0 * 32);
        floatx4 v1 = *(const floatx4*)(Arow + k0 * 32 + 4);
        af[k0] = pk8(v0, v1);
    }

    #pragma unroll
    for (int k = 0; k < 8; ++k) {
        int row = k * 2 + (l >> 5);
        int g = (l & 31) ^ (row & 7);
        load_lds16(WTb + (size_t)w * 4096 + row * 256 + g * 8, &bst[w][k * 512]);
    }

    #pragma unroll
    for (int j = 0; j < 4; ++j) {       // ct = w + 4j -> head j, d-slice w
        WAIT_VM0();
        floatx4 acc = {0.f, 0.f, 0.f, 0.f};
        #pragma unroll
        for (int k0 = 0; k0 < 8; ++k0) {
            int p = ((k0 << 2) + q) ^ (rl & 7);
            short8 bf = *(const short8*)(&bst[w][rl * 256 + p * 8]);
            acc = __builtin_amdgcn_mfma_f32_16x16x32_bf16(af[k0], bf, acc, 0, 0, 0);
        }
        WAIT_LGKM0();
        if (j < 3) {
            int ctn = w + 4 * (j + 1);
            #pragma unroll
            for (int k = 0; k < 8; ++k) {
                int row = k * 2 + (l >> 5);
                int g = (l & 31) ^ (row & 7);
                load_lds16(WTb + (size_t)ctn * 4096 + row * 256 + g * 8, &bst[w][k * 512]);
            }
        }

        intx2 pr;
        pr[0] = (int)pk2(acc[0], acc[1]);
        pr[1] = (int)pk2(acc[2], acc[3]);
        *(intx2*)(WhT + ((size_t)(bb * 4 + j) * 64 + w * 16 + rl) * NN + n0 + q * 4) = pr;

        float av1 = a1[j * 64 + w * 16 + rl] * LOG2E;
        float av2 = a2[j * 64 + w * 16 + rl] * LOG2E;
        #pragma unroll
        for (int i = 0; i < 4; ++i) {
            float p1 = acc[i] * av1, p2 = acc[i] * av2;
            #pragma unroll
            for (int off = 1; off < 16; off <<= 1) {
                p1 += __shfl_xor(p1, off, 64);
                p2 += __shfl_xor(p2, off, 64);
            }
            if (rl == 0) { redsi[w][j][q * 4 + i] = p1; redsj[w][j][q * 4 + i] = p2; }
        }
    }
    __syncthreads();

    if (t < 64) {
        int head = t >> 4, row = t & 15;
        si[(size_t)(bb * 4 + head) * NN + n0 + row] =
            redsi[0][head][row] + redsi[1][head][row] + redsi[2][head][row] + redsi[3][head][row];
    } else if (t < 128) {
        int u = t - 64;
        int head = u >> 4, row = u & 15;
        sj[(size_t)(bb * 4 + head) * NN + n0 + row] =
            redsj[0][head][row] + redsj[1][head][row] + redsj[2][head][row] + redsj[3][head][row];
    }
}

// ================= K2: attn (8-wave m-split, DOUBLE-BUFFERED DMA, counted vmcnt) + proj + LN =================
// grid = 512 x 512t. Wave w: head hh = w&3, m-half e = w>>2. Per iter:
//   scores(it) -> fence -> issue DMA(it+1) into buf^1 -> s_waitcnt vmcnt(4) -> MFMA on buf.
// The 4 newest outstanding vmem ops at the wait are exactly DMA(it+1); all older (incl. DMA(it)) retired.
// LDS 74.5 KB (bst dbuf 64K + pl/hm/red union 10K) -> 2 blocks/CU, 16 waves/CU.
__global__ __launch_bounds__(512, 4) void attn_proj_kernel(
    const unsigned* __restrict__ adjm,
    const __hip_bfloat16* __restrict__ WhT,
    const float* __restrict__ si, const float* __restrict__ sj,
    const __hip_bfloat16* __restrict__ pwb,
    const float* __restrict__ h,
    const float* __restrict__ proj_b, const float* __restrict__ gamma,
    const float* __restrict__ beta,
    float* __restrict__ out)
{
    __shared__ __align__(16) char smem[76288];
    auto bst   = reinterpret_cast<__hip_bfloat16 (*)[2][2048]>(smem);          // [8][2][2048] dbuf, 65536 B
    auto pl    = reinterpret_cast<__hip_bfloat16 (*)[16][40]>(smem + 65536);   // [8][16][40], 10240 B (dead at S1)
    auto hm    = reinterpret_cast<__hip_bfloat16 (*)[264]>(smem + 65536);      // [16][264], 8448 B (live after S2; overlays pl)
    auto red   = reinterpret_cast<float (*)[8][16]>(smem + 65536 + 8448);      // [2][8][16], 1024 B (live after S3)
    auto lsums = reinterpret_cast<float (*)[4][16]>(smem + 75776);             // [2][4][16], 512 B
    // acc-combine buffer overlays bst (dead after loop): [head][lane][16 vals, pad 20]
    float (*accx)[64][20] = reinterpret_cast<float (*)[64][20]>(smem);

    int bx = blockIdx.x, t = threadIdx.x;
    int w = t >> 6, l = t & 63;
    int hh = w & 3, e = w >> 2;
    int rl = l & 15, q = l >> 4;
    int b = bx >> 6, n0 = (bx & 63) * 16;
    int bh = b * 4 + hh;
    int r0 = bx * 16;

    int r = l >> 2, cg = l & 3;          // score roles: row r, 8-entry chunk cg (within 32-m half)
    float sii = si[(size_t)bh * NN + n0 + r];
    const float* sjr = sj + (size_t)bh * NN;
    const unsigned* amrow = adjm + (size_t)(n0 + r) * 32;

    float lsum = 0.f;
    floatx4 acc[4] = { {0,0,0,0}, {0,0,0,0}, {0,0,0,0}, {0,0,0,0} };

    const __hip_bfloat16* Bhead = WhT + (size_t)bh * 64 * NN;

    // DMA lane mapping: load k covers rows k*16+srow (32m = 64B rows, 16 rows / 1KB inst);
    // pre-swizzled source col-group g = c ^ (row&3) so linear LDS dest realizes the XOR layout.
    int srow = l >> 2;                   // 0..15
    int sg = (l & 3) ^ (srow & 3);

    // prologue: issue loads(it=0) into buf0
    #pragma unroll
    for (int k = 0; k < 4; ++k)
        load_lds16(Bhead + (size_t)(k * 16 + srow) * NN + e * 32 + sg * 8, &bst[w][0][k * 512]);

    #pragma unroll 2
    for (int it = 0; it < 16; ++it) {
        int buf = it & 1;
        int mw = it * 64 + e * 32;       // wave's m-base
        // ---- scores over [mw, mw+32) ----
        {
            unsigned bits = amrow[it * 2 + e] >> (cg * 8);
            int mb = mw + cg * 8;
            #pragma unroll
            for (int c4 = 0; c4 < 2; ++c4) {
                floatx4 s4 = *(const floatx4*)(sjr + mb + c4 * 4);
                float pv[4];
                #pragma unroll
                for (int k = 0; k < 4; ++k) {
                    float x = sii + s4[k];
                    x = fmaxf(x, 0.2f * x);                               // leaky (prescaled)
                    x = ((bits >> (c4 * 4 + k)) & 1u) ? x : -1e9f;        // mask -> exp2 = 0
                    pv[k] = exp2f(x);
                    lsum += pv[k];
                }
                intx2 two;
                two[0] = (int)pk2(pv[0], pv[1]);
                two[1] = (int)pk2(pv[2], pv[3]);
                *(intx2*)(&pl[w][r][cg * 8 + c4 * 4]) = two;
            }
        }
        SCHED_FENCE();                   // keep score loads above the DMA issues
        // ---- issue DMA(it+1) into the other buffer, then counted wait for DMA(it) ----
        if (it < 15) {
            int mwn = mw + 64;
            #pragma unroll
            for (int k = 0; k < 4; ++k)
                load_lds16(Bhead + (size_t)(k * 16 + srow) * NN + mwn + sg * 8, &bst[w][buf ^ 1][k * 512]);
            WAIT_VM4();                  // all except the 4 newest (= DMA(it+1)) retired -> tile it landed
        } else {
            WAIT_VM0();
        }
        // ---- MFMA(it): A = P half-tile (K=32), B = swizzled bst[buf] ----
        short8 afr = *(const short8*)(&pl[w][rl][q * 8]);
        #pragma unroll
        for (int dt = 0; dt < 4; ++dt) {
            short8 bfr = *(const short8*)(&bst[w][buf][(dt * 16 + rl) * 32 + (q ^ (rl & 3)) * 8]);
            acc[dt] = __builtin_amdgcn_mfma_f32_16x16x32_bf16(afr, bfr, acc[dt], 0, 0, 0);
        }
        // no lgkm fence: same-buffer DMA reuse is 2 iterations away; the MFMA's own
        // lgkm wait retires these ds_reads before DMA(it+2) is issued (program order).
    }

    // partial softmax denominators: reduce over 4 lanes sharing row r
    lsum += __shfl_xor(lsum, 1, 64);
    lsum += __shfl_xor(lsum, 2, 64);
    if (cg == 0) lsums[e][hh][r] = lsum;

    __syncthreads();    // S1: all waves past last MFMA (bst dead, pl dead); lsums ready

    if (e == 1) {       // stash partial acc for combine
        #pragma unroll
        for (int dt = 0; dt < 4; ++dt) {
            #pragma unroll
            for (int i = 0; i < 4; ++i)
                accx[hh][l][dt * 4 + i] = acc[dt][i];
        }
    }
    __syncthreads();    // S2: accx ready

    if (e == 0) {       // combine halves, apply 1/denominator, write hm
        float riv[4];
        #pragma unroll
        for (int i = 0; i < 4; ++i)
            riv[i] = 1.f / (lsums[0][hh][q * 4 + i] + lsums[1][hh][q * 4 + i]);
        #pragma unroll
        for (int dt = 0; dt < 4; ++dt) {
            #pragma unroll
            for (int i = 0; i < 4; ++i) {
                float v = acc[dt][i] + accx[hh][l][dt * 4 + i];
                unsigned uv = (__float_as_uint(v * riv[i]) + 0x8000u) >> 16;
                hm[q * 4 + i][hh * 64 + dt * 16 + rl] = __ushort_as_bfloat16((unsigned short)uv);
            }
        }
    }
    __syncthreads();    // S3: hm complete (all heads)

    // ---- proj: A from hm, B direct from L2-hot pwb; wave w tiles ct = w + 8j ----
    short8 paf[8];
    #pragma unroll
    for (int k0 = 0; k0 < 8; ++k0) paf[k0] = *(const short8*)(&hm[rl][q * 8 + k0 * 32]);

    floatx4 pacc[2];
    #pragma unroll
    for (int j = 0; j < 2; ++j) {
        int ct = w + 8 * j;
        const __hip_bfloat16* Bp = pwb + (size_t)(ct * 16 + rl) * 256 + q * 8;
        floatx4 a = {0.f, 0.f, 0.f, 0.f};
        #pragma unroll
        for (int k0 = 0; k0 < 8; ++k0) {
            short8 bfp = *(const short8*)(Bp + k0 * 32);
            a = __builtin_amdgcn_mfma_f32_16x16x32_bf16(paf[k0], bfp, a, 0, 0, 0);
        }
        pacc[j] = a;
    }

    // bias + residual + LayerNorm (8 waves x 2 col-tiles each)
    float ps[4] = {0.f, 0.f, 0.f, 0.f};
    #pragma unroll
    for (int j = 0; j < 2; ++j) {
        int col = (w + 8 * j) * 16 + rl;
        float pb = proj_b[col];
        #pragma unroll
        for (int i = 0; i < 4; ++i) {
            float v = pacc[j][i] + pb + h[(size_t)(r0 + q * 4 + i) * 256 + col];
            pacc[j][i] = v;
            ps[i] += v;
        }
    }
    #pragma unroll
    for (int i = 0; i < 4; ++i) {
        float s = ps[i];
        #pragma unroll
        for (int off = 1; off < 16; off <<= 1) s += __shfl_xor(s, off, 64);
        ps[i] = s;
    }
    if (rl == 0) {
        for (int i = 0; i < 4; ++i) red[0][w][q * 4 + i] = ps[i];
    }
    __syncthreads();
    float mu[4];
    #pragma unroll
    for (int i = 0; i < 4; ++i) {
        int row = q * 4 + i;
        float s = 0.f;
        #pragma unroll
        for (int ww = 0; ww < 8; ++ww) s += red[0][ww][row];
        mu[i] = s * (1.f / 256.f);
    }
    float vs[4] = {0.f, 0.f, 0.f, 0.f};
    #pragma unroll
    for (int j = 0; j < 2; ++j) {
        #pragma unroll
        for (int i = 0; i < 4; ++i) { float cv = pacc[j][i] - mu[i]; vs[i] += cv * cv; }
    }
    #pragma unroll
    for (int i = 0; i < 4; ++i) {
        float s = vs[i];
        #pragma unroll
        for (int off = 1; off < 16; off <<= 1) s += __shfl_xor(s, off, 64);
        vs[i] = s;
    }
    if (rl == 0) {
        for (int i = 0; i < 4; ++i) red[1][w][q * 4 + i] = vs[i];
    }
    __syncthreads();
    float rs[4];
    #pragma unroll
    for (int i = 0; i < 4; ++i) {
        int row = q * 4 + i;
        float s = 0.f;
        #pragma unroll
        for (int ww = 0; ww < 8; ++ww) s += red[1][ww][row];
        rs[i] = rsqrtf(s * (1.f / 256.f) + 1e-5f);
    }
    #pragma unroll
    for (int j = 0; j < 2; ++j) {
        int col = (w + 8 * j) * 16 + rl;
        float g = gamma[col], be = beta[col];
        #pragma unroll
        for (int i = 0; i < 4; ++i)
            out[(size_t)(r0 + q * 4 + i) * 256 + col] = (pacc[j][i] - mu[i]) * rs[i] * g + be;
    }
}

extern "C" void kernel_launch(void* const* d_in, const int* in_sizes, int n_in,
                              void* d_out, int out_size, void* d_ws, size_t ws_size,
                              hipStream_t stream) {
    const float* h      = (const float*)d_in[0];
    const int*   adj    = (const int*)d_in[1];
    const float* W      = (const float*)d_in[2];
    const float* a1     = (const float*)d_in[3];
    const float* a2     = (const float*)d_in[4];
    const float* proj_w = (const float*)d_in[5];
    const float* proj_b = (const float*)d_in[6];
    const float* gamma  = (const float*)d_in[7];
    const float* beta   = (const float*)d_in[8];
    float* out = (float*)d_out;

    char* ws = (char*)d_ws;
    __hip_bfloat16* WhT = (__hip_bfloat16*)ws;   ws += (size_t)32 * 64 * NN * 2;   // 4 MB
    __hip_bfloat16* WTb = (__hip_bfloat16*)ws;   ws += 256 * 256 * 2;              // 128 KB
    __hip_bfloat16* pwb = (__hip_bfloat16*)ws;   ws += 256 * 256 * 2;              // 128 KB
    float* si = (float*)ws;                      ws += (size_t)32 * NN * 4;        // 128 KB
    float* sj = (float*)ws;                      ws += (size_t)32 * NN * 4;        // 128 KB
    unsigned* adjm = (unsigned*)ws;              ws += (size_t)NN * 32 * 4;        // 128 KB

    prep_kernel<<<160, 256, 0, stream>>>(W, proj_w, adj, WTb, pwb, adjm);
    wh_kernel<<<512, 256, 0, stream>>>(h, WTb, a1, a2, WhT, si, sj);
    attn_proj_kernel<<<512, 512, 0, stream>>>(adjm, WhT, si, sj, pwb, h, proj_b, gamma, beta, out);
}

// Round 4
// 121.176 us; speedup vs baseline: 1.1592x; 1.0118x over previous
//
#include <hip/hip_runtime.h>
#include <hip/hip_bf16.h>

#define NN 1024
#define LOG2E 1.44269504088896f

typedef __attribute__((ext_vector_type(8))) short short8;
typedef __attribute__((ext_vector_type(4))) float floatx4;
typedef __attribute__((ext_vector_type(4))) int intx4;
typedef __attribute__((ext_vector_type(2))) int intx2;

#define WAIT_VM0()   asm volatile("s_waitcnt vmcnt(0)" ::: "memory")
#define WAIT_VM4()   asm volatile("s_waitcnt vmcnt(4)" ::: "memory")
#define WAIT_LGKM0() asm volatile("s_waitcnt lgkmcnt(0)" ::: "memory")
#define SCHED_FENCE() asm volatile("" ::: "memory")

// fast f32->bf16 (round-half-up) pack of two floats into one dword
static __device__ __forceinline__ unsigned pk2(float f0, float f1) {
    unsigned u0 = __float_as_uint(f0) + 0x8000u;
    unsigned u1 = __float_as_uint(f1) + 0x8000u;
    return __builtin_amdgcn_perm(u1, u0, 0x07060302u);   // [u1.hi16 : u0.hi16]
}
static __device__ __forceinline__ short8 pk8(floatx4 v0, floatx4 v1) {
    union { intx4 i; short8 s; } u;
    u.i[0] = (int)pk2(v0[0], v0[1]); u.i[1] = (int)pk2(v0[2], v0[3]);
    u.i[2] = (int)pk2(v1[0], v1[1]); u.i[3] = (int)pk2(v1[2], v1[3]);
    return u.s;
}
// async global->LDS, 16B/lane, dest = ldsbase + lane*16
static __device__ __forceinline__ void load_lds16(const void* gsrc, void* lds) {
    __builtin_amdgcn_global_load_lds(
        (const __attribute__((address_space(1))) void*)gsrc,
        (__attribute__((address_space(3))) void*)lds, 16, 0, 0);
}

// ================= K0: prep — WTb transpose, pwb cast, adj bitmask =================
__global__ __launch_bounds__(256) void prep_kernel(
    const float* __restrict__ W, const float* __restrict__ proj_w,
    const int* __restrict__ adj,
    __hip_bfloat16* __restrict__ WTb,    // [256 o][256 k], o = hh*64+d
    __hip_bfloat16* __restrict__ pwb,    // [256 o][256 k]
    unsigned* __restrict__ adjm)         // [1024][32]
{
    int blk = blockIdx.x, t = threadIdx.x;
    if (blk < 16) {
        int o = blk * 16 + (t >> 4);
        int hh = o >> 6, d = o & 63;
        #pragma unroll
        for (int kk = 0; kk < 16; ++kk) {
            int k = (t & 15) + 16 * kk;
            WTb[(size_t)o * 256 + k] = __float2bfloat16(W[((size_t)hh * 256 + k) * 64 + d]);
        }
    } else if (blk < 32) {
        size_t base = (size_t)(blk - 16) * 4096 + (size_t)t * 16;
        #pragma unroll
        for (int k = 0; k < 16; k += 8) {
            floatx4 v0 = *(const floatx4*)(proj_w + base + k);
            floatx4 v1 = *(const floatx4*)(proj_w + base + k + 4);
            *(short8*)(pwb + base + k) = pk8(v0, v1);
        }
    } else {
        int n = (blk - 32) * 8 + (t >> 5);
        int wd = t & 31;
        const int* arow = adj + (size_t)n * NN + wd * 32;
        unsigned bits = 0;
        #pragma unroll
        for (int j4 = 0; j4 < 8; ++j4) {
            intx4 v = *(const intx4*)(arow + j4 * 4);
            #pragma unroll
            for (int j = 0; j < 4; ++j) if (v[j] != 0) bits |= (1u << (j4 * 4 + j));
        }
        adjm[(size_t)n * 32 + wd] = bits;
    }
}

// ================= K1: Wh GEMM — async staging (round-0 proven) + TILED/SWIZZLED WhT store =================
// WhTt layout: tile T = bh*32 + (n>>5); within tile (2048 elems = 64d x 32m):
//   elem(d, m5) = d*32 + ((m5>>3) ^ (d&3))*8 + (m5&7)      [XOR col-group swizzle baked in]
// This is byte-for-byte the LDS image K2 stages, so K2's DMA is a linear 4KB copy.
__global__ __launch_bounds__(256) void wh_kernel(
    const float* __restrict__ h,
    const __hip_bfloat16* __restrict__ WTb,
    const float* __restrict__ a1, const float* __restrict__ a2,
    __hip_bfloat16* __restrict__ WhTt,  // [32 bh][32 tiles][2048]
    float* __restrict__ si, float* __restrict__ sj)   // PRESCALED by log2e
{
    int t = threadIdx.x;
    int w = t >> 6, l = t & 63;
    int rl = l & 15, q = l >> 4;
    int r0 = blockIdx.x * 16;
    int bb = r0 >> 10, n0 = r0 & 1023;

    __shared__ __align__(16) __hip_bfloat16 bst[4][4096];
    __shared__ float redsi[4][4][16];
    __shared__ float redsj[4][4][16];

    short8 af[8];
    const float* Arow = h + (size_t)(r0 + rl) * 256 + q * 8;
    #pragma unroll
    for (int k0 = 0; k0 < 8; ++k0) {
        floatx4 v0 = *(const floatx4*)(Arow + k0 * 32);
        floatx4 v1 = *(const floatx4*)(Arow + k0 * 32 + 4);
        af[k0] = pk8(v0, v1);
    }

    #pragma unroll
    for (int k = 0; k < 8; ++k) {
        int row = k * 2 + (l >> 5);
        int g = (l & 31) ^ (row & 7);
        load_lds16(WTb + (size_t)w * 4096 + row * 256 + g * 8, &bst[w][k * 512]);
    }

    // store-address pieces (per lane, invariant over j): d = w*16+rl
    int d = w * 16 + rl;
    int s = (n0 & 31) + q * 4;           // within-tile m start (multiple of 4)
    int g = s >> 3;
    int mi = s & 7;                      // 0 or 4
    size_t toff = (size_t)d * 32 + ((g ^ (d & 3)) * 8) + mi;
    size_t tbase = ((size_t)bb * 4) * 32 + (n0 >> 5);   // tile index for j=0 (head 0)

    #pragma unroll
    for (int j = 0; j < 4; ++j) {       // ct = w + 4j -> head j, d-slice w
        WAIT_VM0();
        floatx4 acc = {0.f, 0.f, 0.f, 0.f};
        #pragma unroll
        for (int k0 = 0; k0 < 8; ++k0) {
            int p = ((k0 << 2) + q) ^ (rl & 7);
            short8 bf = *(const short8*)(&bst[w][rl * 256 + p * 8]);
            acc = __builtin_amdgcn_mfma_f32_16x16x32_bf16(af[k0], bf, acc, 0, 0, 0);
        }
        WAIT_LGKM0();
        if (j < 3) {
            int ctn = w + 4 * (j + 1);
            #pragma unroll
            for (int k = 0; k < 8; ++k) {
                int row = k * 2 + (l >> 5);
                int gg = (l & 31) ^ (row & 7);
                load_lds16(WTb + (size_t)ctn * 4096 + row * 256 + gg * 8, &bst[w][k * 512]);
            }
        }

        // tiled+swizzled store: tile = (bb*4+j)*32 + (n0>>5)
        intx2 pr;
        pr[0] = (int)pk2(acc[0], acc[1]);
        pr[1] = (int)pk2(acc[2], acc[3]);
        *(intx2*)(WhTt + (tbase + (size_t)j * 32) * 2048 + toff) = pr;

        float av1 = a1[j * 64 + w * 16 + rl] * LOG2E;
        float av2 = a2[j * 64 + w * 16 + rl] * LOG2E;
        #pragma unroll
        for (int i = 0; i < 4; ++i) {
            float p1 = acc[i] * av1, p2 = acc[i] * av2;
            #pragma unroll
            for (int off = 1; off < 16; off <<= 1) {
                p1 += __shfl_xor(p1, off, 64);
                p2 += __shfl_xor(p2, off, 64);
            }
            if (rl == 0) { redsi[w][j][q * 4 + i] = p1; redsj[w][j][q * 4 + i] = p2; }
        }
    }
    __syncthreads();

    if (t < 64) {
        int head = t >> 4, row = t & 15;
        si[(size_t)(bb * 4 + head) * NN + n0 + row] =
            redsi[0][head][row] + redsi[1][head][row] + redsi[2][head][row] + redsi[3][head][row];
    } else if (t < 128) {
        int u = t - 64;
        int head = u >> 4, row = u & 15;
        sj[(size_t)(bb * 4 + head) * NN + n0 + row] =
            redsj[0][head][row] + redsj[1][head][row] + redsj[2][head][row] + redsj[3][head][row];
    }
}

// ================= K2: attn (8-wave m-split, dbuf DMA over LINEAR tiled WhTt) + proj + LN =================
// grid = 512 x 512t. Wave w: head hh = w&3, m-half e = w>>2. Tile (bh, it*2+e) is a
// contiguous pre-swizzled 4KB image -> 4 fully-coalesced global_load_lds per iter.
__global__ __launch_bounds__(512, 4) void attn_proj_kernel(
    const unsigned* __restrict__ adjm,
    const __hip_bfloat16* __restrict__ WhTt,
    const float* __restrict__ si, const float* __restrict__ sj,
    const __hip_bfloat16* __restrict__ pwb,
    const float* __restrict__ h,
    const float* __restrict__ proj_b, const float* __restrict__ gamma,
    const float* __restrict__ beta,
    float* __restrict__ out)
{
    __shared__ __align__(16) char smem[76288];
    auto bst   = reinterpret_cast<__hip_bfloat16 (*)[2][2048]>(smem);          // [8][2][2048] dbuf, 65536 B
    auto pl    = reinterpret_cast<__hip_bfloat16 (*)[16][40]>(smem + 65536);   // [8][16][40], 10240 B (dead at S1)
    auto hm    = reinterpret_cast<__hip_bfloat16 (*)[264]>(smem + 65536);      // [16][264], 8448 B (overlays pl)
    auto red   = reinterpret_cast<float (*)[8][16]>(smem + 65536 + 8448);      // [2][8][16], 1024 B
    auto lsums = reinterpret_cast<float (*)[4][16]>(smem + 75776);             // [2][4][16], 512 B
    float (*accx)[64][20] = reinterpret_cast<float (*)[64][20]>(smem);         // overlays bst after loop

    int bx = blockIdx.x, t = threadIdx.x;
    int w = t >> 6, l = t & 63;
    int hh = w & 3, e = w >> 2;
    int rl = l & 15, q = l >> 4;
    int b = bx >> 6, n0 = (bx & 63) * 16;
    int bh = b * 4 + hh;
    int r0 = bx * 16;

    int r = l >> 2, cg = l & 3;          // score roles: row r, 8-entry chunk cg (within 32-m half)
    float sii = si[(size_t)bh * NN + n0 + r];
    const float* sjr = sj + (size_t)bh * NN;
    const unsigned* amrow = adjm + (size_t)(n0 + r) * 32;

    float lsum = 0.f;
    floatx4 acc[4] = { {0,0,0,0}, {0,0,0,0}, {0,0,0,0}, {0,0,0,0} };

    // per-wave tile stream: tiles (bh, it*2 + e), each a linear 4KB copy
    const __hip_bfloat16* Tbase = WhTt + ((size_t)bh * 32 + e) * 2048 + l * 8;

    // prologue: issue loads(it=0) into buf0
    #pragma unroll
    for (int k = 0; k < 4; ++k)
        load_lds16(Tbase + k * 512, &bst[w][0][k * 512]);

    #pragma unroll 2
    for (int it = 0; it < 16; ++it) {
        int buf = it & 1;
        int mw = it * 64 + e * 32;       // wave's m-base
        // ---- scores over [mw, mw+32) ----
        {
            unsigned bits = amrow[it * 2 + e] >> (cg * 8);
            int mb = mw + cg * 8;
            #pragma unroll
            for (int c4 = 0; c4 < 2; ++c4) {
                floatx4 s4 = *(const floatx4*)(sjr + mb + c4 * 4);
                float pv[4];
                #pragma unroll
                for (int k = 0; k < 4; ++k) {
                    float x = sii + s4[k];
                    x = fmaxf(x, 0.2f * x);                               // leaky (prescaled)
                    x = ((bits >> (c4 * 4 + k)) & 1u) ? x : -1e9f;        // mask -> exp2 = 0
                    pv[k] = exp2f(x);
                    lsum += pv[k];
                }
                intx2 two;
                two[0] = (int)pk2(pv[0], pv[1]);
                two[1] = (int)pk2(pv[2], pv[3]);
                *(intx2*)(&pl[w][r][cg * 8 + c4 * 4]) = two;
            }
        }
        SCHED_FENCE();                   // keep score loads above the DMA issues
        // ---- issue DMA(it+1) into the other buffer, then counted wait for DMA(it) ----
        if (it < 15) {
            const __hip_bfloat16* Tn = Tbase + (size_t)(it + 1) * 2 * 2048;
            #pragma unroll
            for (int k = 0; k < 4; ++k)
                load_lds16(Tn + k * 512, &bst[w][buf ^ 1][k * 512]);
            WAIT_VM4();                  // all except the 4 newest (= DMA(it+1)) retired
        } else {
            WAIT_VM0();
        }
        // ---- MFMA(it): A = P half-tile (K=32), B = swizzled bst[buf] ----
        short8 afr = *(const short8*)(&pl[w][rl][q * 8]);
        #pragma unroll
        for (int dt = 0; dt < 4; ++dt) {
            short8 bfr = *(const short8*)(&bst[w][buf][(dt * 16 + rl) * 32 + (q ^ (rl & 3)) * 8]);
            acc[dt] = __builtin_amdgcn_mfma_f32_16x16x32_bf16(afr, bfr, acc[dt], 0, 0, 0);
        }
        // same-buffer DMA reuse is 2 iterations away; MFMA's own lgkm wait orders the ds_reads.
    }

    // partial softmax denominators: reduce over 4 lanes sharing row r
    lsum += __shfl_xor(lsum, 1, 64);
    lsum += __shfl_xor(lsum, 2, 64);
    if (cg == 0) lsums[e][hh][r] = lsum;

    __syncthreads();    // S1: all waves past last MFMA (bst dead, pl dead); lsums ready

    if (e == 1) {       // stash partial acc for combine
        #pragma unroll
        for (int dt = 0; dt < 4; ++dt) {
            #pragma unroll
            for (int i = 0; i < 4; ++i)
                accx[hh][l][dt * 4 + i] = acc[dt][i];
        }
    }
    __syncthreads();    // S2: accx ready

    if (e == 0) {       // combine halves, apply 1/denominator, write hm
        float riv[4];
        #pragma unroll
        for (int i = 0; i < 4; ++i)
            riv[i] = 1.f / (lsums[0][hh][q * 4 + i] + lsums[1][hh][q * 4 + i]);
        #pragma unroll
        for (int dt = 0; dt < 4; ++dt) {
            #pragma unroll
            for (int i = 0; i < 4; ++i) {
                float v = acc[dt][i] + accx[hh][l][dt * 4 + i];
                unsigned uv = (__float_as_uint(v * riv[i]) + 0x8000u) >> 16;
                hm[q * 4 + i][hh * 64 + dt * 16 + rl] = __ushort_as_bfloat16((unsigned short)uv);
            }
        }
    }
    __syncthreads();    // S3: hm complete (all heads)

    // ---- proj: A from hm, B direct from L2-hot pwb; wave w tiles ct = w + 8j ----
    short8 paf[8];
    #pragma unroll
    for (int k0 = 0; k0 < 8; ++k0) paf[k0] = *(const short8*)(&hm[rl][q * 8 + k0 * 32]);

    floatx4 pacc[2];
    #pragma unroll
    for (int j = 0; j < 2; ++j) {
        int ct = w + 8 * j;
        const __hip_bfloat16* Bp = pwb + (size_t)(ct * 16 + rl) * 256 + q * 8;
        floatx4 a = {0.f, 0.f, 0.f, 0.f};
        #pragma unroll
        for (int k0 = 0; k0 < 8; ++k0) {
            short8 bfp = *(const short8*)(Bp + k0 * 32);
            a = __builtin_amdgcn_mfma_f32_16x16x32_bf16(paf[k0], bfp, a, 0, 0, 0);
        }
        pacc[j] = a;
    }

    // bias + residual + LayerNorm (8 waves x 2 col-tiles each)
    float ps[4] = {0.f, 0.f, 0.f, 0.f};
    #pragma unroll
    for (int j = 0; j < 2; ++j) {
        int col = (w + 8 * j) * 16 + rl;
        float pb = proj_b[col];
        #pragma unroll
        for (int i = 0; i < 4; ++i) {
            float v = pacc[j][i] + pb + h[(size_t)(r0 + q * 4 + i) * 256 + col];
            pacc[j][i] = v;
            ps[i] += v;
        }
    }
    #pragma unroll
    for (int i = 0; i < 4; ++i) {
        float s = ps[i];
        #pragma unroll
        for (int off = 1; off < 16; off <<= 1) s += __shfl_xor(s, off, 64);
        ps[i] = s;
    }
    if (rl == 0) {
        for (int i = 0; i < 4; ++i) red[0][w][q * 4 + i] = ps[i];
    }
    __syncthreads();
    float mu[4];
    #pragma unroll
    for (int i = 0; i < 4; ++i) {
        int row = q * 4 + i;
        float s = 0.f;
        #pragma unroll
        for (int ww = 0; ww < 8; ++ww) s += red[0][ww][row];
        mu[i] = s * (1.f / 256.f);
    }
    float vs[4] = {0.f, 0.f, 0.f, 0.f};
    #pragma unroll
    for (int j = 0; j < 2; ++j) {
        #pragma unroll
        for (int i = 0; i < 4; ++i) { float cv = pacc[j][i] - mu[i]; vs[i] += cv * cv; }
    }
    #pragma unroll
    for (int i = 0; i < 4; ++i) {
        float s = vs[i];
        #pragma unroll
        for (int off = 1; off < 16; off <<= 1) s += __shfl_xor(s, off, 64);
        vs[i] = s;
    }
    if (rl == 0) {
        for (int i = 0; i < 4; ++i) red[1][w][q * 4 + i] = vs[i];
    }
    __syncthreads();
    float rs[4];
    #pragma unroll
    for (int i = 0; i < 4; ++i) {
        int row = q * 4 + i;
        float s = 0.f;
        #pragma unroll
        for (int ww = 0; ww < 8; ++ww) s += red[1][ww][row];
        rs[i] = rsqrtf(s * (1.f / 256.f) + 1e-5f);
    }
    #pragma unroll
    for (int j = 0; j < 2; ++j) {
        int col = (w + 8 * j) * 16 + rl;
        float g = gamma[col], be = beta[col];
        #pragma unroll
        for (int i = 0; i < 4; ++i)
            out[(size_t)(r0 + q * 4 + i) * 256 + col] = (pacc[j][i] - mu[i]) * rs[i] * g + be;
    }
}

extern "C" void kernel_launch(void* const* d_in, const int* in_sizes, int n_in,
                              void* d_out, int out_size, void* d_ws, size_t ws_size,
                              hipStream_t stream) {
    const float* h      = (const float*)d_in[0];
    const int*   adj    = (const int*)d_in[1];
    const float* W      = (const float*)d_in[2];
    const float* a1     = (const float*)d_in[3];
    const float* a2     = (const float*)d_in[4];
    const float* proj_w = (const float*)d_in[5];
    const float* proj_b = (const float*)d_in[6];
    const float* gamma  = (const float*)d_in[7];
    const float* beta   = (const float*)d_in[8];
    float* out = (float*)d_out;

    char* ws = (char*)d_ws;
    __hip_bfloat16* WhTt = (__hip_bfloat16*)ws;  ws += (size_t)32 * 32 * 2048 * 2;  // 4 MB
    __hip_bfloat16* WTb = (__hip_bfloat16*)ws;   ws += 256 * 256 * 2;               // 128 KB
    __hip_bfloat16* pwb = (__hip_bfloat16*)ws;   ws += 256 * 256 * 2;               // 128 KB
    float* si = (float*)ws;                      ws += (size_t)32 * NN * 4;         // 128 KB
    float* sj = (float*)ws;                      ws += (size_t)32 * NN * 4;         // 128 KB
    unsigned* adjm = (unsigned*)ws;              ws += (size_t)NN * 32 * 4;         // 128 KB

    prep_kernel<<<160, 256, 0, stream>>>(W, proj_w, adj, WTb, pwb, adjm);
    wh_kernel<<<512, 256, 0, stream>>>(h, WTb, a1, a2, WhTt, si, sj);
    attn_proj_kernel<<<512, 512, 0, stream>>>(adjm, WhTt, si, sj, pwb, h, proj_b, gamma, beta, out);
}

// Round 5
// 120.536 us; speedup vs baseline: 1.1653x; 1.0053x over previous
//
#include <hip/hip_runtime.h>
#include <hip/hip_bf16.h>

#define NN 1024
#define LOG2E 1.44269504088896f

typedef __attribute__((ext_vector_type(8))) short short8;
typedef __attribute__((ext_vector_type(4))) float floatx4;
typedef __attribute__((ext_vector_type(4))) int intx4;
typedef __attribute__((ext_vector_type(2))) int intx2;

#define WAIT_VM0()   asm volatile("s_waitcnt vmcnt(0)" ::: "memory")
#define WAIT_VM4()   asm volatile("s_waitcnt vmcnt(4)" ::: "memory")
#define WAIT_LGKM0() asm volatile("s_waitcnt lgkmcnt(0)" ::: "memory")
#define SCHED_FENCE() asm volatile("" ::: "memory")

// fast f32->bf16 (round-half-up) pack of two floats into one dword
static __device__ __forceinline__ unsigned pk2(float f0, float f1) {
    unsigned u0 = __float_as_uint(f0) + 0x8000u;
    unsigned u1 = __float_as_uint(f1) + 0x8000u;
    return __builtin_amdgcn_perm(u1, u0, 0x07060302u);   // [u1.hi16 : u0.hi16]
}
static __device__ __forceinline__ short8 pk8(floatx4 v0, floatx4 v1) {
    union { intx4 i; short8 s; } u;
    u.i[0] = (int)pk2(v0[0], v0[1]); u.i[1] = (int)pk2(v0[2], v0[3]);
    u.i[2] = (int)pk2(v1[0], v1[1]); u.i[3] = (int)pk2(v1[2], v1[3]);
    return u.s;
}
// async global->LDS, 16B/lane, dest = ldsbase + lane*16
static __device__ __forceinline__ void load_lds16(const void* gsrc, void* lds) {
    __builtin_amdgcn_global_load_lds(
        (const __attribute__((address_space(1))) void*)gsrc,
        (__attribute__((address_space(3))) void*)lds, 16, 0, 0);
}

// ================= K0: prep — WTb transpose, pwb cast, adj bitmask =================
__global__ __launch_bounds__(256) void prep_kernel(
    const float* __restrict__ W, const float* __restrict__ proj_w,
    const int* __restrict__ adj,
    __hip_bfloat16* __restrict__ WTb,    // [256 o][256 k], o = hh*64+d
    __hip_bfloat16* __restrict__ pwb,    // [256 o][256 k]
    unsigned* __restrict__ adjm)         // [1024][32]
{
    int blk = blockIdx.x, t = threadIdx.x;
    if (blk < 16) {
        int o = blk * 16 + (t >> 4);
        int hh = o >> 6, d = o & 63;
        #pragma unroll
        for (int kk = 0; kk < 16; ++kk) {
            int k = (t & 15) + 16 * kk;
            WTb[(size_t)o * 256 + k] = __float2bfloat16(W[((size_t)hh * 256 + k) * 64 + d]);
        }
    } else if (blk < 32) {
        size_t base = (size_t)(blk - 16) * 4096 + (size_t)t * 16;
        #pragma unroll
        for (int k = 0; k < 16; k += 8) {
            floatx4 v0 = *(const floatx4*)(proj_w + base + k);
            floatx4 v1 = *(const floatx4*)(proj_w + base + k + 4);
            *(short8*)(pwb + base + k) = pk8(v0, v1);
        }
    } else {
        int n = (blk - 32) * 8 + (t >> 5);
        int wd = t & 31;
        const int* arow = adj + (size_t)n * NN + wd * 32;
        unsigned bits = 0;
        #pragma unroll
        for (int j4 = 0; j4 < 8; ++j4) {
            intx4 v = *(const intx4*)(arow + j4 * 4);
            #pragma unroll
            for (int j = 0; j < 4; ++j) if (v[j] != 0) bits |= (1u << (j4 * 4 + j));
        }
        adjm[(size_t)n * 32 + wd] = bits;
    }
}

// ================= K1: Wh GEMM — REWRITTEN: 256 blocks x 512t, full WTb reuse, 2 staged phases =================
// Block = (batch bb, 32-token tile tb). Wave w: row-tile rt = w>>2, d-slice ds = w&3.
// WTb (128 KB, shared by ALL blocks) staged once per block in two 64 KB phases (heads {0,1} then {2,3});
// 8 DMA/wave/phase, one barrier-drain per phase (vs 4 drains x re-stage in the old 512-block version).
// Output WhTt: same tiled+swizzled layout as R4 (tile T = bh*32 + (n>>5); elem(d,m5) = d*32 + ((m5>>3)^(d&3))*8 + (m5&7)).
__global__ __launch_bounds__(512) void wh_kernel(
    const float* __restrict__ h,
    const __hip_bfloat16* __restrict__ WTb,
    const float* __restrict__ a1, const float* __restrict__ a2,
    __hip_bfloat16* __restrict__ WhTt,  // [32 bh][32 tiles][2048]
    float* __restrict__ si, float* __restrict__ sj)   // PRESCALED by log2e
{
    __shared__ __align__(16) __hip_bfloat16 WTbs[8][4096];   // 64 KB: 8 tiles (16o x 256k), XOR image
    __shared__ float redsi[2][4][4][16];                     // [rt][ds][head][row]
    __shared__ float redsj[2][4][4][16];

    int t = threadIdx.x;
    int w = t >> 6, l = t & 63;
    int rt = w >> 2, ds = w & 3;
    int rl = l & 15, q = l >> 4;
    int bx = blockIdx.x;
    int bb = bx >> 5, tb = bx & 31;

    // A-frags: token row n' = tb*32 + rt*16 + rl of batch bb (f32 -> bf16 pack)
    short8 af[8];
    const float* Arow = h + ((size_t)bb * 1024 + tb * 32 + rt * 16 + rl) * 256 + q * 8;
    #pragma unroll
    for (int k0 = 0; k0 < 8; ++k0) {
        floatx4 v0 = *(const floatx4*)(Arow + k0 * 32);
        floatx4 v1 = *(const floatx4*)(Arow + k0 * 32 + 4);
        af[k0] = pk8(v0, v1);
    }

    // WhTt within-tile offset: d = ds*16+rl (C col), m5 = rt*16 + q*4 + i (C row within 32-tile)
    int d = ds * 16 + rl;
    int s = rt * 16 + q * 4;
    size_t toff = (size_t)d * 32 + (((s >> 3) ^ (d & 3)) * 8) + (s & 7);
    int srow_ = l >> 5;

    #pragma unroll
    for (int ph = 0; ph < 2; ++ph) {
        if (ph) __syncthreads();         // all phase-0 ds_reads retired before overwrite
        // stage tile (ph*8 + w): instr k covers rows k*2+(l>>5); pre-swizzled src col-group
        #pragma unroll
        for (int k = 0; k < 8; ++k) {
            int row = k * 2 + srow_;
            int g = (l & 31) ^ (row & 7);
            load_lds16(WTb + (size_t)(ph * 128 + w * 16 + row) * 256 + g * 8, &WTbs[w][k * 512]);
        }
        __syncthreads();                 // implicit vmcnt(0): all 64 KB landed, visible to all waves

        #pragma unroll
        for (int jj = 0; jj < 2; ++jj) {
            int head = ph * 2 + jj;
            int lt = ds + 4 * jj;        // local tile: ct = ds + 4*head = ph*8 + lt
            floatx4 acc = {0.f, 0.f, 0.f, 0.f};
            #pragma unroll
            for (int k0 = 0; k0 < 8; ++k0) {
                int p = ((k0 << 2) + q) ^ (rl & 7);
                short8 bf = *(const short8*)(&WTbs[lt][rl * 256 + p * 8]);
                acc = __builtin_amdgcn_mfma_f32_16x16x32_bf16(af[k0], bf, acc, 0, 0, 0);
            }

            // tiled+swizzled store: tile T = (bb*4+head)*32 + tb
            intx2 pr;
            pr[0] = (int)pk2(acc[0], acc[1]);
            pr[1] = (int)pk2(acc[2], acc[3]);
            *(intx2*)(WhTt + ((size_t)(bb * 4 + head) * 32 + tb) * 2048 + toff) = pr;

            // si/sj partials (prescaled by log2e), reduce over this wave's 16 d's
            float av1 = a1[head * 64 + d] * LOG2E;
            float av2 = a2[head * 64 + d] * LOG2E;
            #pragma unroll
            for (int i = 0; i < 4; ++i) {
                float p1 = acc[i] * av1, p2 = acc[i] * av2;
                #pragma unroll
                for (int off = 1; off < 16; off <<= 1) {
                    p1 += __shfl_xor(p1, off, 64);
                    p2 += __shfl_xor(p2, off, 64);
                }
                if (rl == 0) { redsi[rt][ds][head][q * 4 + i] = p1; redsj[rt][ds][head][q * 4 + i] = p2; }
            }
        }
    }
    __syncthreads();

    if (t < 128) {
        int head = t >> 5, u = t & 31, rt2 = u >> 4, row = u & 15;
        si[(size_t)(bb * 4 + head) * NN + tb * 32 + rt2 * 16 + row] =
            redsi[rt2][0][head][row] + redsi[rt2][1][head][row] +
            redsi[rt2][2][head][row] + redsi[rt2][3][head][row];
    } else if (t < 256) {
        int u2 = t - 128;
        int head = u2 >> 5, u = u2 & 31, rt2 = u >> 4, row = u & 15;
        sj[(size_t)(bb * 4 + head) * NN + tb * 32 + rt2 * 16 + row] =
            redsj[rt2][0][head][row] + redsj[rt2][1][head][row] +
            redsj[rt2][2][head][row] + redsj[rt2][3][head][row];
    }
}

// ================= K2: attn (8-wave m-split, dbuf DMA over LINEAR tiled WhTt) + proj + LN =================
// BYTE-IDENTICAL to round 4 (kept frozen to isolate the K1 change).
__global__ __launch_bounds__(512, 4) void attn_proj_kernel(
    const unsigned* __restrict__ adjm,
    const __hip_bfloat16* __restrict__ WhTt,
    const float* __restrict__ si, const float* __restrict__ sj,
    const __hip_bfloat16* __restrict__ pwb,
    const float* __restrict__ h,
    const float* __restrict__ proj_b, const float* __restrict__ gamma,
    const float* __restrict__ beta,
    float* __restrict__ out)
{
    __shared__ __align__(16) char smem[76288];
    auto bst   = reinterpret_cast<__hip_bfloat16 (*)[2][2048]>(smem);          // [8][2][2048] dbuf, 65536 B
    auto pl    = reinterpret_cast<__hip_bfloat16 (*)[16][40]>(smem + 65536);   // [8][16][40], 10240 B (dead at S1)
    auto hm    = reinterpret_cast<__hip_bfloat16 (*)[264]>(smem + 65536);      // [16][264], 8448 B (overlays pl)
    auto red   = reinterpret_cast<float (*)[8][16]>(smem + 65536 + 8448);      // [2][8][16], 1024 B
    auto lsums = reinterpret_cast<float (*)[4][16]>(smem + 75776);             // [2][4][16], 512 B
    float (*accx)[64][20] = reinterpret_cast<float (*)[64][20]>(smem);         // overlays bst after loop

    int bx = blockIdx.x, t = threadIdx.x;
    int w = t >> 6, l = t & 63;
    int hh = w & 3, e = w >> 2;
    int rl = l & 15, q = l >> 4;
    int b = bx >> 6, n0 = (bx & 63) * 16;
    int bh = b * 4 + hh;
    int r0 = bx * 16;

    int r = l >> 2, cg = l & 3;          // score roles: row r, 8-entry chunk cg (within 32-m half)
    float sii = si[(size_t)bh * NN + n0 + r];
    const float* sjr = sj + (size_t)bh * NN;
    const unsigned* amrow = adjm + (size_t)(n0 + r) * 32;

    float lsum = 0.f;
    floatx4 acc[4] = { {0,0,0,0}, {0,0,0,0}, {0,0,0,0}, {0,0,0,0} };

    // per-wave tile stream: tiles (bh, it*2 + e), each a linear 4KB copy
    const __hip_bfloat16* Tbase = WhTt + ((size_t)bh * 32 + e) * 2048 + l * 8;

    // prologue: issue loads(it=0) into buf0
    #pragma unroll
    for (int k = 0; k < 4; ++k)
        load_lds16(Tbase + k * 512, &bst[w][0][k * 512]);

    #pragma unroll 2
    for (int it = 0; it < 16; ++it) {
        int buf = it & 1;
        int mw = it * 64 + e * 32;       // wave's m-base
        // ---- scores over [mw, mw+32) ----
        {
            unsigned bits = amrow[it * 2 + e] >> (cg * 8);
            int mb = mw + cg * 8;
            #pragma unroll
            for (int c4 = 0; c4 < 2; ++c4) {
                floatx4 s4 = *(const floatx4*)(sjr + mb + c4 * 4);
                float pv[4];
                #pragma unroll
                for (int k = 0; k < 4; ++k) {
                    float x = sii + s4[k];
                    x = fmaxf(x, 0.2f * x);                               // leaky (prescaled)
                    x = ((bits >> (c4 * 4 + k)) & 1u) ? x : -1e9f;        // mask -> exp2 = 0
                    pv[k] = exp2f(x);
                    lsum += pv[k];
                }
                intx2 two;
                two[0] = (int)pk2(pv[0], pv[1]);
                two[1] = (int)pk2(pv[2], pv[3]);
                *(intx2*)(&pl[w][r][cg * 8 + c4 * 4]) = two;
            }
        }
        SCHED_FENCE();                   // keep score loads above the DMA issues
        // ---- issue DMA(it+1) into the other buffer, then counted wait for DMA(it) ----
        if (it < 15) {
            const __hip_bfloat16* Tn = Tbase + (size_t)(it + 1) * 2 * 2048;
            #pragma unroll
            for (int k = 0; k < 4; ++k)
                load_lds16(Tn + k * 512, &bst[w][buf ^ 1][k * 512]);
            WAIT_VM4();                  // all except the 4 newest (= DMA(it+1)) retired
        } else {
            WAIT_VM0();
        }
        // ---- MFMA(it): A = P half-tile (K=32), B = swizzled bst[buf] ----
        short8 afr = *(const short8*)(&pl[w][rl][q * 8]);
        #pragma unroll
        for (int dt = 0; dt < 4; ++dt) {
            short8 bfr = *(const short8*)(&bst[w][buf][(dt * 16 + rl) * 32 + (q ^ (rl & 3)) * 8]);
            acc[dt] = __builtin_amdgcn_mfma_f32_16x16x32_bf16(afr, bfr, acc[dt], 0, 0, 0);
        }
        // same-buffer DMA reuse is 2 iterations away; MFMA's own lgkm wait orders the ds_reads.
    }

    // partial softmax denominators: reduce over 4 lanes sharing row r
    lsum += __shfl_xor(lsum, 1, 64);
    lsum += __shfl_xor(lsum, 2, 64);
    if (cg == 0) lsums[e][hh][r] = lsum;

    __syncthreads();    // S1: all waves past last MFMA (bst dead, pl dead); lsums ready

    if (e == 1) {       // stash partial acc for combine
        #pragma unroll
        for (int dt = 0; dt < 4; ++dt) {
            #pragma unroll
            for (int i = 0; i < 4; ++i)
                accx[hh][l][dt * 4 + i] = acc[dt][i];
        }
    }
    __syncthreads();    // S2: accx ready

    if (e == 0) {       // combine halves, apply 1/denominator, write hm
        float riv[4];
        #pragma unroll
        for (int i = 0; i < 4; ++i)
            riv[i] = 1.f / (lsums[0][hh][q * 4 + i] + lsums[1][hh][q * 4 + i]);
        #pragma unroll
        for (int dt = 0; dt < 4; ++dt) {
            #pragma unroll
            for (int i = 0; i < 4; ++i) {
                float v = acc[dt][i] + accx[hh][l][dt * 4 + i];
                unsigned uv = (__float_as_uint(v * riv[i]) + 0x8000u) >> 16;
                hm[q * 4 + i][hh * 64 + dt * 16 + rl] = __ushort_as_bfloat16((unsigned short)uv);
            }
        }
    }
    __syncthreads();    // S3: hm complete (all heads)

    // ---- proj: A from hm, B direct from L2-hot pwb; wave w tiles ct = w + 8j ----
    short8 paf[8];
    #pragma unroll
    for (int k0 = 0; k0 < 8; ++k0) paf[k0] = *(const short8*)(&hm[rl][q * 8 + k0 * 32]);

    floatx4 pacc[2];
    #pragma unroll
    for (int j = 0; j < 2; ++j) {
        int ct = w + 8 * j;
        const __hip_bfloat16* Bp = pwb + (size_t)(ct * 16 + rl) * 256 + q * 8;
        floatx4 a = {0.f, 0.f, 0.f, 0.f};
        #pragma unroll
        for (int k0 = 0; k0 < 8; ++k0) {
            short8 bfp = *(const short8*)(Bp + k0 * 32);
            a = __builtin_amdgcn_mfma_f32_16x16x32_bf16(paf[k0], bfp, a, 0, 0, 0);
        }
        pacc[j] = a;
    }

    // bias + residual + LayerNorm (8 waves x 2 col-tiles each)
    float ps[4] = {0.f, 0.f, 0.f, 0.f};
    #pragma unroll
    for (int j = 0; j < 2; ++j) {
        int col = (w + 8 * j) * 16 + rl;
        float pb = proj_b[col];
        #pragma unroll
        for (int i = 0; i < 4; ++i) {
            float v = pacc[j][i] + pb + h[(size_t)(r0 + q * 4 + i) * 256 + col];
            pacc[j][i] = v;
            ps[i] += v;
        }
    }
    #pragma unroll
    for (int i = 0; i < 4; ++i) {
        float s = ps[i];
        #pragma unroll
        for (int off = 1; off < 16; off <<= 1) s += __shfl_xor(s, off, 64);
        ps[i] = s;
    }
    if (rl == 0) {
        for (int i = 0; i < 4; ++i) red[0][w][q * 4 + i] = ps[i];
    }
    __syncthreads();
    float mu[4];
    #pragma unroll
    for (int i = 0; i < 4; ++i) {
        int row = q * 4 + i;
        float s = 0.f;
        #pragma unroll
        for (int ww = 0; ww < 8; ++ww) s += red[0][ww][row];
        mu[i] = s * (1.f / 256.f);
    }
    float vs[4] = {0.f, 0.f, 0.f, 0.f};
    #pragma unroll
    for (int j = 0; j < 2; ++j) {
        #pragma unroll
        for (int i = 0; i < 4; ++i) { float cv = pacc[j][i] - mu[i]; vs[i] += cv * cv; }
    }
    #pragma unroll
    for (int i = 0; i < 4; ++i) {
        float s = vs[i];
        #pragma unroll
        for (int off = 1; off < 16; off <<= 1) s += __shfl_xor(s, off, 64);
        vs[i] = s;
    }
    if (rl == 0) {
        for (int i = 0; i < 4; ++i) red[1][w][q * 4 + i] = vs[i];
    }
    __syncthreads();
    float rs[4];
    #pragma unroll
    for (int i = 0; i < 4; ++i) {
        int row = q * 4 + i;
        float s = 0.f;
        #pragma unroll
        for (int ww = 0; ww < 8; ++ww) s += red[1][ww][row];
        rs[i] = rsqrtf(s * (1.f / 256.f) + 1e-5f);
    }
    #pragma unroll
    for (int j = 0; j < 2; ++j) {
        int col = (w + 8 * j) * 16 + rl;
        float g = gamma[col], be = beta[col];
        #pragma unroll
        for (int i = 0; i < 4; ++i)
            out[(size_t)(r0 + q * 4 + i) * 256 + col] = (pacc[j][i] - mu[i]) * rs[i] * g + be;
    }
}

extern "C" void kernel_launch(void* const* d_in, const int* in_sizes, int n_in,
                              void* d_out, int out_size, void* d_ws, size_t ws_size,
                              hipStream_t stream) {
    const float* h      = (const float*)d_in[0];
    const int*   adj    = (const int*)d_in[1];
    const float* W      = (const float*)d_in[2];
    const float* a1     = (const float*)d_in[3];
    const float* a2     = (const float*)d_in[4];
    const float* proj_w = (const float*)d_in[5];
    const float* proj_b = (const float*)d_in[6];
    const float* gamma  = (const float*)d_in[7];
    const float* beta   = (const float*)d_in[8];
    float* out = (float*)d_out;

    char* ws = (char*)d_ws;
    __hip_bfloat16* WhTt = (__hip_bfloat16*)ws;  ws += (size_t)32 * 32 * 2048 * 2;  // 4 MB
    __hip_bfloat16* WTb = (__hip_bfloat16*)ws;   ws += 256 * 256 * 2;               // 128 KB
    __hip_bfloat16* pwb = (__hip_bfloat16*)ws;   ws += 256 * 256 * 2;               // 128 KB
    float* si = (float*)ws;                      ws += (size_t)32 * NN * 4;         // 128 KB
    float* sj = (float*)ws;                      ws += (size_t)32 * NN * 4;         // 128 KB
    unsigned* adjm = (unsigned*)ws;              ws += (size_t)NN * 32 * 4;         // 128 KB

    prep_kernel<<<160, 256, 0, stream>>>(W, proj_w, adj, WTb, pwb, adjm);
    wh_kernel<<<256, 512, 0, stream>>>(h, WTb, a1, a2, WhTt, si, sj);
    attn_proj_kernel<<<512, 512, 0, stream>>>(adjm, WhTt, si, sj, pwb, h, proj_b, gamma, beta, out);
}